// Round 9
// baseline (228.359 us; speedup 1.0000x reference)
//
#include <hip/hip_runtime.h>

// GovernanceAwareAttention on MI355X (gfx950). Round 9.
// Governance bias is constant along key axis -> softmax invariant -> only
// `influence` needs gov_scores (fused into gemm). bf16 MFMA + flash attn.
//
// R9: (1) hs->bf16 conversion fused into gemm: A staged as f32 via
// global_load_lds with granule-XOR swizzle (f32 rows are 128B = 0 mod 32
// banks -> same structural 4-way conflict found in R7 attn), LDS->frag
// conversion via v_perm packs on gemm's idle VALU. hsB round-trip (8MB W +
// 8MB R) and the 2048-block prep section deleted. (2) attn kt-body phase-
// batched (all S-MFMAs, then all softmax, then all PV) for cross-chain ILP
// at the fixed 2 waves/SIMD occupancy.

typedef unsigned short u16;
typedef __attribute__((ext_vector_type(8))) short bf16x8;   // 8 bf16 = 4 VGPR
typedef __attribute__((ext_vector_type(4))) float f32x4;
typedef __attribute__((ext_vector_type(16))) float f32x16;
typedef __attribute__((ext_vector_type(2))) float f32x2;
typedef __attribute__((ext_vector_type(4))) u16 u16x4;
typedef __attribute__((ext_vector_type(4))) float float4v;
typedef __attribute__((ext_vector_type(4))) unsigned uint4v;

typedef const __attribute__((address_space(1))) void gvoid_t;
typedef __attribute__((address_space(3))) void lvoid_t;

__device__ __forceinline__ void gl_lds16(const void* g, void* l) {
  // async global->LDS, 16B/lane; LDS dest is wave-uniform base + lane*16
  __builtin_amdgcn_global_load_lds((gvoid_t*)g, (lvoid_t*)l, 16, 0, 0);
}

__device__ __forceinline__ u16 f2bf(float x) {  // RNE f32->bf16
  union { float f; unsigned u; } v; v.f = x;
  unsigned r = v.u + 0x7fffu + ((v.u >> 16) & 1u);
  return (u16)(r >> 16);
}
// pack two f32 -> two truncated bf16 in one v_perm_b32 (lo in low half)
__device__ __forceinline__ unsigned pk2(float hi, float lo) {
  union { float f; unsigned u; } a, b; a.f = hi; b.f = lo;
  return __builtin_amdgcn_perm(a.u, b.u, 0x07060302u);
}
__device__ __forceinline__ unsigned pk2u(unsigned hi, unsigned lo) {
  return __builtin_amdgcn_perm(hi, lo, 0x07060302u);
}
__device__ __forceinline__ bf16x8 mk8(unsigned a, unsigned b, unsigned c, unsigned d) {
  union { unsigned u[4]; bf16x8 v; } x;
  x.u[0] = a; x.u[1] = b; x.u[2] = c; x.u[3] = d; return x.v;
}

#if defined(__has_builtin)
#if __has_builtin(__builtin_amdgcn_exp2f)
#define EXP2(x) __builtin_amdgcn_exp2f(x)
#endif
#endif
#ifndef EXP2
#define EXP2(x) exp2f(x)
#endif

// ---------------- prep: W->W^T bf16, gq partials, acc3 zero ----------------
// grid 1088: [0,1024) conv_w, [1024,1088) gq partials.
__global__ void prep(const float* __restrict__ W0, const float* __restrict__ W1,
                     const float* __restrict__ W2, const float* __restrict__ W3,
                     const float* __restrict__ ge, const float* __restrict__ Wgq,
                     u16* __restrict__ WB, float* __restrict__ gq_part,
                     float* __restrict__ acc3) {
  __shared__ __align__(16) u16 T[64][72];
  int bx = blockIdx.x, tid = threadIdx.x;
  if (bx < 1024) {                       // W[k][n] -> WB[mat*1024+n][k], LDS xpose
    int mat = bx >> 8, sub = bx & 255;
    const float* W = (mat == 0) ? W0 : (mat == 1) ? W1 : (mat == 2) ? W2 : W3;
    int k0 = (sub >> 4) * 64, n0 = (sub & 15) * 64;
#pragma unroll
    for (int p = 0; p < 4; ++p) {
      int chunk = p * 256 + tid;
      int row = chunk >> 4, cp = chunk & 15;
      float4v v = *(const float4v*)&W[(size_t)(k0 + row) * 1024 + n0 + cp * 4];
      u16x4 o; o.x = f2bf(v.x); o.y = f2bf(v.y); o.z = f2bf(v.z); o.w = f2bf(v.w);
      *(u16x4*)&T[row][cp * 4] = o;
    }
    __syncthreads();
#pragma unroll
    for (int p = 0; p < 2; ++p) {
      int chunk = p * 256 + tid;
      int nrow = chunk >> 3, cp = chunk & 7;
      bf16x8 v;
#pragma unroll
      for (int e = 0; e < 8; ++e) v[e] = (short)T[cp * 8 + e][nrow];
      *(bf16x8*)&WB[(size_t)(mat * 1024 + n0 + nrow) * 1024 + k0 + cp * 8] = v;
    }
    return;
  }
  {                                      // gq partial sums (+ acc3 zero)
    int idx = bx - 1024;                 // 64 blocks
    if (idx == 0 && tid < 3) acc3[tid] = 0.f;
    int kb = idx >> 1, b = idx & 1;
    int col0 = tid * 4;
    float4v s = {0.f, 0.f, 0.f, 0.f};
    for (int k = kb * 32; k < kb * 32 + 32; ++k) {
      float g = ge[b * 1024 + k];
      float4v w = *(const float4v*)&Wgq[(size_t)k * 1024 + col0];
      s.x += g * w.x; s.y += g * w.y; s.z += g * w.z; s.w += g * w.w;
    }
    *(float4v*)&gq_part[(size_t)idx * 1024 + col0] = s;  // [kb*2+b][1024]
  }
}

// ---------------- projection GEMM (A = f32 hs, fused convert) ----------------
// grid 1024. mat==3 blocks compute influence in-register; GK never stored.
// K -> Kt4[b][h][g=k/4][s:2048][4];  V -> Vt4[b][g=s/4][d:1024][4].
__global__ __launch_bounds__(256, 3) void gemm_qkvg(
    const float* __restrict__ A, const u16* __restrict__ Bw,
    const float* __restrict__ bq, const float* __restrict__ bk,
    const float* __restrict__ bv, const float* __restrict__ bgk,
    const float* __restrict__ bgq, const float* __restrict__ gq_part,
    u16* __restrict__ Qb, u16* __restrict__ Kt4, u16* __restrict__ Vt4,
    float* __restrict__ acc3) {
  __shared__ __align__(16) float As[2][4096];   // [row:128][g:8 xor row&7][4 f32]
  __shared__ __align__(16) u16 Bs[2][128 * 32];
  __shared__ float redI[4];
  const int tid = threadIdx.x, lane = tid & 63, wv = tid >> 6;
  const int li = lane & 15, quad = lane >> 4;
  const int bid = blockIdx.x;
  const int nb = bid & 31, mb = bid >> 5;
  const float* Ap = A + (size_t)(mb * 128) * 1024;
  const u16* Bp = Bw + (size_t)(nb * 128) * 1024;
  const int wm0 = (wv >> 1) * 64, wn0 = (wv & 1) * 64;

  // staging source indices
  const int arow = (lane >> 3);                   // + j*8
  const int agsrc = (lane & 7) ^ arow;            // granule XOR row&7
  const int brow = (lane >> 2);                   // + j*16
  const int bco = lane & 3;

  f32x4 acc[4][4];
#pragma unroll
  for (int t = 0; t < 4; ++t)
#pragma unroll
    for (int u = 0; u < 4; ++u) acc[t][u] = (f32x4){0.f, 0.f, 0.f, 0.f};

  // prologue: stage kt=0 into buf 0
#pragma unroll
  for (int jj = 0; jj < 4; ++jj) {      // A f32: 16 KB, 4 issues/wave
    int j = wv * 4 + jj;
    gl_lds16(Ap + (size_t)(j * 8 + arow) * 1024 + agsrc * 4, &As[0][j * 256]);
  }
#pragma unroll
  for (int jj = 0; jj < 2; ++jj) {      // B bf16: 8 KB, 2 issues/wave
    int j = wv * 2 + jj;
    gl_lds16(Bp + (size_t)(j * 16 + brow) * 1024 + bco * 8, &Bs[0][j * 512]);
  }

  for (int kt = 0; kt < 32; ++kt) {
    const int cur = kt & 1;
    __syncthreads();                     // drains loads for buf cur
    if (kt < 31) {                       // prefetch kt+1 into other buffer
#pragma unroll
      for (int jj = 0; jj < 4; ++jj) {
        int j = wv * 4 + jj;
        gl_lds16(Ap + (size_t)(j * 8 + arow) * 1024 + (kt + 1) * 32 + agsrc * 4,
                 &As[cur ^ 1][j * 256]);
      }
#pragma unroll
      for (int jj = 0; jj < 2; ++jj) {
        int j = wv * 2 + jj;
        gl_lds16(Bp + (size_t)(j * 16 + brow) * 1024 + (kt + 1) * 32 + bco * 8,
                 &Bs[cur ^ 1][j * 512]);
      }
    }
    bf16x8 af[4], bf[4];
#pragma unroll
    for (int t = 0; t < 4; ++t) {        // A frag: 2 b128 f32 + 4 perms
      int row = wm0 + t * 16 + li;
      int rx = row & 7;
      uint4v v = *(const uint4v*)&As[cur][row * 32 + ((quad * 2) ^ rx) * 4];
      uint4v w = *(const uint4v*)&As[cur][row * 32 + ((quad * 2 + 1) ^ rx) * 4];
      af[t] = mk8(pk2u(v.y, v.x), pk2u(v.w, v.z), pk2u(w.y, w.x), pk2u(w.w, w.z));
    }
#pragma unroll
    for (int u = 0; u < 4; ++u)
      bf[u] = *(const bf16x8*)&Bs[cur][(wn0 + u * 16 + li) * 32 + quad * 8];
#pragma unroll
    for (int t = 0; t < 4; ++t)
#pragma unroll
      for (int u = 0; u < 4; ++u)
        acc[t][u] = __builtin_amdgcn_mfma_f32_16x16x32_bf16(af[t], bf[u], acc[t][u], 0, 0, 0);
  }

  const int nbase = nb * 128;
  const int mat = nbase >> 10;           // block never straddles matrices
  if (mat == 3) {
    // ---- fused influence: wave owns 64 rows x 1 full head (64 cols) ----
    const int colbase = nbase & 1023;
    const int bat = (mb * 128) >> 11;    // batch index of this block's rows
    float gqv[4], bgkv[4];
#pragma unroll
    for (int u2 = 0; u2 < 4; ++u2) {
      int col = colbase + wn0 + u2 * 16 + li;
      float g = bgq[col];
      for (int kb = 0; kb < 32; ++kb)
        g += gq_part[(size_t)(kb * 2 + bat) * 1024 + col];
      gqv[u2] = g;
      bgkv[u2] = bgk[col];
    }
    float infl = 0.f;
#pragma unroll
    for (int t = 0; t < 4; ++t)
#pragma unroll
      for (int r = 0; r < 4; ++r) {
        float v = (acc[t][0][r] + bgkv[0]) * gqv[0];
        v = __builtin_fmaf(acc[t][1][r] + bgkv[1], gqv[1], v);
        v = __builtin_fmaf(acc[t][2][r] + bgkv[2], gqv[2], v);
        v = __builtin_fmaf(acc[t][3][r] + bgkv[3], gqv[3], v);
        v += __shfl_xor(v, 1, 64); v += __shfl_xor(v, 2, 64);
        v += __shfl_xor(v, 4, 64); v += __shfl_xor(v, 8, 64);
        infl += fabsf(v);              // all 16 li-lanes hold same v
      }
    infl = (li == 0) ? infl : 0.f;
    infl += __shfl_xor(infl, 16, 64);
    infl += __shfl_xor(infl, 32, 64);
    if (lane == 0) redI[wv] = infl;
    __syncthreads();
    if (tid == 0) atomicAdd(&acc3[2], redI[0] + redI[1] + redI[2] + redI[3]);
  } else if (mat == 2) {
    // V -> Vt4[b][g=s/4][d:1024][4s], one b64 per (t,u)
#pragma unroll
    for (int t = 0; t < 4; ++t)
#pragma unroll
      for (int u = 0; u < 4; ++u) {
        int col = (nbase & 1023) + wn0 + u * 16 + li;
        float bb = bv[col];
        int row = mb * 128 + wm0 + t * 16 + quad * 4;  // s%4 == 0
        int b = row >> 11, s = row & 2047, g = s >> 2;
        uint2 w;
        w.x = pk2(acc[t][u][1] + bb, acc[t][u][0] + bb);
        w.y = pk2(acc[t][u][3] + bb, acc[t][u][2] + bb);
        *(uint2*)&Vt4[(((size_t)b * 512 + g) * 1024 + col) * 4] = w;
      }
  } else if (mat == 1) {
    // K -> Kt4[b][h][g=k/4][s:2048][4k], scalar stores (8B-local per r)
#pragma unroll
    for (int t = 0; t < 4; ++t)
#pragma unroll
      for (int u = 0; u < 4; ++u) {
        int col = (nbase & 1023) + wn0 + u * 16 + li;
        int h = col >> 6, g = (col & 63) >> 2, r4 = col & 3;
        float bb = bk[col];
        u16* base = &Kt4[(((size_t)h * 16 + g) * 2048) * 4 + r4];
#pragma unroll
        for (int r = 0; r < 4; ++r) {
          int row = mb * 128 + wm0 + t * 16 + quad * 4 + r;
          int b = row >> 11, s = row & 2047;
          base[((size_t)b * 16 * 16 * 2048 + s) * 4] = f2bf(acc[t][u][r] + bb);
        }
      }
  } else {
    // Q (pre-scaled by 1/sqrt(64) * log2(e) for exp2-based softmax)
#pragma unroll
    for (int t = 0; t < 4; ++t)
#pragma unroll
      for (int u = 0; u < 4; ++u) {
        int col = (nbase & 1023) + wn0 + u * 16 + li;
        float bb = bq[col];
#pragma unroll
        for (int r = 0; r < 4; ++r) {
          int row = mb * 128 + wm0 + t * 16 + quad * 4 + r;
          Qb[(size_t)row * 1024 + col] = f2bf((acc[t][u][r] + bb) * 0.18033688f);
        }
      }
  }
}

// ---------------- flash attention: 32x32 MFMA, phase-batched -----------------
// grid 512 x 256. bh = bx&31 (XCD-L2 locality), qb = bx>>5.
__global__ __launch_bounds__(256, 2) void attn_kernel(
    const u16* __restrict__ Qb, const u16* __restrict__ Kt4,
    const u16* __restrict__ Vt4, float* __restrict__ out,
    float* __restrict__ acc3 /*[0]=ent,[1]=conc*/) {
  __shared__ __align__(16) u16 Ks[2][8192];   // [g:16][s_phys:128][4k]
  __shared__ __align__(16) u16 Vs[2][8192];   // [g:32][d_phys:64][4s]
  __shared__ float red[8];

  const int tid = threadIdx.x, lane = tid & 63, wv = tid >> 6;
  const int q_l = lane & 31, half = lane >> 5;
  const int x8 = half << 3;              // row-XOR for bank spread
  const int bx = blockIdx.x;
  const int bh = bx & 31, qb = bx >> 5;
  const int b = bh >> 4, h = bh & 15;

  const u16* Qp = Qb + (size_t)(b * 2048 + qb * 128 + wv * 32 + q_l) * 1024 + h * 64;
  const u16* Kp4 = Kt4 + ((size_t)(b * 16 + h) * 16) * 2048 * 4;
  const u16* Vp4 = Vt4 + ((size_t)b * 512 * 1024 + h * 64) * 4;

  // Q^T B-frags in registers: lane (q=q_l, half) holds k = s*16 + half*8 + j
  bf16x8 qf[4];
#pragma unroll
  for (int s = 0; s < 4; ++s)
    qf[s] = *(const bf16x8*)&Qp[s * 16 + half * 8];

  f32x2 mx2 = {-3.0e38f, -3.0e38f}, ps2 = {0.f, 0.f}, es2 = {0.f, 0.f};
  f32x16 accO[2];   // O^T: rows d = dt*32 + (reg&3)+8*(reg>>2)+4*half, col q
#pragma unroll
  for (int dt = 0; dt < 2; ++dt)
#pragma unroll
    for (int r = 0; r < 16; ++r) accO[dt][r] = 0.f;

  // staging lane->source indices (XOR-8 so wave-halves hit different banks)
  const int ksrc = (2 * lane);           // ^x8g per column below
  const int vlane_d = 2 * (lane & 31);

  // prologue: stage tile 0 into buf 0
#pragma unroll
  for (int jj = 0; jj < 4; ++jj) {
    int g = wv * 4 + jj;
    int xg = ((g >> 1) & 1) << 3;
    gl_lds16(Kp4 + ((size_t)g * 2048 + (ksrc ^ xg)) * 4, &Ks[0][g * 512]);
  }
#pragma unroll
  for (int jj = 0; jj < 4; ++jj) {
    int j = wv * 4 + jj;
    int g = 2 * j + (lane >> 5);
    int xg = (g & 1) << 3;
    gl_lds16(Vp4 + ((size_t)g * 1024 + (vlane_d ^ xg)) * 4, &Vs[0][j * 512]);
  }

  for (int kt = 0; kt < 16; ++kt) {
    const int cur = kt & 1;
    __syncthreads();                     // drains tile-kt loads
    if (kt < 15) {                       // prefetch kt+1; compute hides it
#pragma unroll
      for (int jj = 0; jj < 4; ++jj) {
        int g = wv * 4 + jj;
        int xg = ((g >> 1) & 1) << 3;
        gl_lds16(Kp4 + ((size_t)g * 2048 + (kt + 1) * 128 + (ksrc ^ xg)) * 4,
                 &Ks[cur ^ 1][g * 512]);
      }
#pragma unroll
      for (int jj = 0; jj < 4; ++jj) {
        int j = wv * 4 + jj;
        int g = 2 * j + (lane >> 5);
        int xg = (g & 1) << 3;
        gl_lds16(Vp4 + ((size_t)((kt + 1) * 32 + g) * 1024 + (vlane_d ^ xg)) * 4,
                 &Vs[cur ^ 1][j * 512]);
      }
    }
    const u16* KsC = &Ks[cur][0];
    const u16* VsC = &Vs[cur][0];

    // ---- phase 1: all four 32-key S^T tiles (independent MFMA chains) ----
    f32x16 c[4];
#pragma unroll
    for (int u = 0; u < 4; ++u) {
      const int keyp = (u * 32 + q_l) ^ x8;    // physical row (XOR-8 stored)
      f32x16 cc;
#pragma unroll
      for (int r = 0; r < 16; ++r) cc[r] = 0.f;
#pragma unroll
      for (int s = 0; s < 4; ++s) {
        int g0 = s * 4 + half * 2;
        uint2 k0 = *(const uint2*)&KsC[g0 * 512 + keyp * 4];
        uint2 k1 = *(const uint2*)&KsC[(g0 + 1) * 512 + keyp * 4];
        cc = __builtin_amdgcn_mfma_f32_32x32x16_bf16(
            mk8(k0.x, k0.y, k1.x, k1.y), qf[s], cc, 0, 0, 0);
      }
      c[u] = cc;
    }
    // ---- phase 2: softmax stats + exp over all 64 scores ----
#pragma unroll
    for (int u = 0; u < 4; ++u)
#pragma unroll
      for (int r = 0; r < 8; ++r) {
        f32x2 sv = {c[u][2 * r], c[u][2 * r + 1]};
        mx2 = __builtin_elementwise_max(mx2, sv);
        f32x2 pe = {EXP2(sv.x), EXP2(sv.y)};
        ps2 += pe;
        es2 += pe * sv;                  // v_pk_fma_f32
        c[u][2 * r] = pe.x; c[u][2 * r + 1] = pe.y;
      }
    // ---- phase 3: pack + PV (C regs ARE the B-operand pattern) ----
#pragma unroll
    for (int u = 0; u < 4; ++u) {
      bf16x8 bf0 = mk8(pk2(c[u][1], c[u][0]),   pk2(c[u][3], c[u][2]),
                       pk2(c[u][5], c[u][4]),   pk2(c[u][7], c[u][6]));
      bf16x8 bf1 = mk8(pk2(c[u][9], c[u][8]),   pk2(c[u][11], c[u][10]),
                       pk2(c[u][13], c[u][12]), pk2(c[u][15], c[u][14]));
#pragma unroll
      for (int dt = 0; dt < 2; ++dt) {
        int dp = (dt * 32 + q_l) ^ x8;   // physical d row
        uint2 v0 = *(const uint2*)&VsC[(u * 8 + half) * 256 + dp * 4];
        uint2 v1 = *(const uint2*)&VsC[(u * 8 + 2 + half) * 256 + dp * 4];
        accO[dt] = __builtin_amdgcn_mfma_f32_32x32x16_bf16(
            mk8(v0.x, v0.y, v1.x, v1.y), bf0, accO[dt], 0, 0, 0);
        uint2 v2 = *(const uint2*)&VsC[(u * 8 + 4 + half) * 256 + dp * 4];
        uint2 v3 = *(const uint2*)&VsC[(u * 8 + 6 + half) * 256 + dp * 4];
        accO[dt] = __builtin_amdgcn_mfma_f32_32x32x16_bf16(
            mk8(v2.x, v2.y, v3.x, v3.y), bf1, accO[dt], 0, 0, 0);
      }
    }
  }

  // epilogue: each lane owns query q_l (duplicated across half)
  float l_st = ps2.x + ps2.y, e_st = es2.x + es2.y, m_st = fmaxf(mx2.x, mx2.y);
  float lsum = l_st + __shfl_xor(l_st, 32, 64);
  float esum = e_st + __shfl_xor(e_st, 32, 64);
  float mm = fmaxf(m_st, __shfl_xor(m_st, 32, 64));
  float inv = 1.0f / lsum;
  float entw = __logf(lsum) - 0.69314718f * esum * inv;  // s' in log2 units
  float concw = EXP2(mm) * inv;

  float* outp = out + (size_t)(b * 2048 + qb * 128 + wv * 32 + q_l) * 1024 + h * 64;
#pragma unroll
  for (int dt = 0; dt < 2; ++dt)
#pragma unroll
    for (int g = 0; g < 4; ++g) {
      float4v o;
      o.x = accO[dt][4 * g + 0] * inv; o.y = accO[dt][4 * g + 1] * inv;
      o.z = accO[dt][4 * g + 2] * inv; o.w = accO[dt][4 * g + 3] * inv;
      *(float4v*)&outp[dt * 32 + 8 * g + 4 * half] = o;
    }

#pragma unroll
  for (int off = 1; off < 64; off <<= 1) {
    entw += __shfl_xor(entw, off, 64);
    concw += __shfl_xor(concw, off, 64);
  }
  if (lane == 0) { red[wv] = entw * 0.5f; red[4 + wv] = concw * 0.5f; }  // /2 dup
  __syncthreads();
  if (tid == 0) {
    atomicAdd(&acc3[0], red[0] + red[1] + red[2] + red[3]);
    atomicAdd(&acc3[1], red[4] + red[5] + red[6] + red[7]);
  }
}

__global__ void finalize(const float* __restrict__ acc3, float* __restrict__ out) {
  if (threadIdx.x == 0) {
    out[0] = acc3[0] * (1.f / 65536.f);  // entropy
    out[1] = acc3[2] * (1.f / 65536.f);  // influence
    out[2] = acc3[1] * (1.f / 65536.f);  // concentration
  }
}

extern "C" void kernel_launch(void* const* d_in, const int* in_sizes, int n_in,
                              void* d_out, int out_size, void* d_ws, size_t ws_size,
                              hipStream_t stream) {
  (void)in_sizes; (void)n_in; (void)out_size; (void)ws_size;
  const float* hs  = (const float*)d_in[0];
  const float* ge  = (const float*)d_in[1];
  const float* Wq  = (const float*)d_in[2];
  const float* bq  = (const float*)d_in[3];
  const float* Wk  = (const float*)d_in[4];
  const float* bk  = (const float*)d_in[5];
  const float* Wv  = (const float*)d_in[6];
  const float* bv  = (const float*)d_in[7];
  const float* Wgq = (const float*)d_in[8];
  const float* bgq = (const float*)d_in[9];
  const float* Wgk = (const float*)d_in[10];
  const float* bgk = (const float*)d_in[11];

  char* ws = (char*)d_ws;
  u16* WB   = (u16*)(ws);
  u16* Qb   = (u16*)(ws + (size_t)(8 << 20));
  u16* Kt4  = (u16*)(ws + (size_t)(16 << 20));
  u16* Vt4  = (u16*)(ws + (size_t)(24 << 20));
  float* gq_part = (float*)(ws + (size_t)(32 << 20));            // 256 KB
  float* acc3    = (float*)(ws + (size_t)(32 << 20) + 524288);
  float* out = (float*)d_out;

  prep<<<1088, 256, 0, stream>>>(Wq, Wk, Wv, Wgk, ge, Wgq, WB, gq_part, acc3);
  gemm_qkvg<<<1024, 256, 0, stream>>>(hs, WB, bq, bk, bv, bgk, bgq, gq_part,
                                      Qb, Kt4, Vt4, acc3);
  attn_kernel<<<512, 256, 0, stream>>>(Qb, Kt4, Vt4, out, acc3);
  finalize<<<1, 64, 0, stream>>>(acc3, out + 4194304);
}

// Round 10
// 215.734 us; speedup vs baseline: 1.0585x; 1.0585x over previous
//
#include <hip/hip_runtime.h>

// GovernanceAwareAttention on MI355X (gfx950). Round 10.
// Governance bias is constant along key axis -> softmax invariant -> only
// `influence` needs gov_scores (fused into gemm). bf16 MFMA + flash attn.
//
// R10: revert R9's f32-A gemm (it doubled A re-read bytes -> FETCH 41->74MB,
// HBM-bound; bf16 hsB round-trip is cheaper because each A-slice is re-read
// by 32 nb-blocks). Keep R9's phase-batched attn. NEW: gemm launch_bounds
// (256,4) -- 33.3KB LDS fits 4 blocks/CU (133KB<160KB, VGPR 76<128) and
// grid 1024 = exactly 4/CU x 256: kills the 256-block tail round that was
// ~1/3 of gemm's runtime at (256,3).

typedef unsigned short u16;
typedef __attribute__((ext_vector_type(8))) short bf16x8;   // 8 bf16 = 4 VGPR
typedef __attribute__((ext_vector_type(4))) float f32x4;
typedef __attribute__((ext_vector_type(16))) float f32x16;
typedef __attribute__((ext_vector_type(2))) float f32x2;
typedef __attribute__((ext_vector_type(4))) u16 u16x4;
typedef __attribute__((ext_vector_type(4))) float float4v;

typedef const __attribute__((address_space(1))) void gvoid_t;
typedef __attribute__((address_space(3))) void lvoid_t;

__device__ __forceinline__ void gl_lds16(const void* g, void* l) {
  // async global->LDS, 16B/lane; LDS dest is wave-uniform base + lane*16
  __builtin_amdgcn_global_load_lds((gvoid_t*)g, (lvoid_t*)l, 16, 0, 0);
}

__device__ __forceinline__ u16 f2bf(float x) {  // RNE f32->bf16
  union { float f; unsigned u; } v; v.f = x;
  unsigned r = v.u + 0x7fffu + ((v.u >> 16) & 1u);
  return (u16)(r >> 16);
}
// pack two f32 -> two truncated bf16 in one v_perm_b32 (lo in low half)
__device__ __forceinline__ unsigned pk2(float hi, float lo) {
  union { float f; unsigned u; } a, b; a.f = hi; b.f = lo;
  return __builtin_amdgcn_perm(a.u, b.u, 0x07060302u);
}
__device__ __forceinline__ bf16x8 mk8(unsigned a, unsigned b, unsigned c, unsigned d) {
  union { unsigned u[4]; bf16x8 v; } x;
  x.u[0] = a; x.u[1] = b; x.u[2] = c; x.u[3] = d; return x.v;
}

#if defined(__has_builtin)
#if __has_builtin(__builtin_amdgcn_exp2f)
#define EXP2(x) __builtin_amdgcn_exp2f(x)
#endif
#endif
#ifndef EXP2
#define EXP2(x) exp2f(x)
#endif

// ---------------- prep: hs->bf16, W->W^T bf16, gq partials, acc3 zero -------
// grid 3136: [0,2048) conv_hs, [2048,3072) conv_w, [3072,3136) gq partials.
__global__ void prep(const float* __restrict__ hs,
                     const float* __restrict__ W0, const float* __restrict__ W1,
                     const float* __restrict__ W2, const float* __restrict__ W3,
                     const float* __restrict__ ge, const float* __restrict__ Wgq,
                     u16* __restrict__ hsB, u16* __restrict__ WB,
                     float* __restrict__ gq_part, float* __restrict__ acc3) {
  __shared__ __align__(16) u16 T[64][72];
  int bx = blockIdx.x, tid = threadIdx.x;
  if (bx < 2048) {                       // hs f32 [4096x1024] -> bf16, RNE
    int i = bx * 256 + tid;
    const float4v* in4 = (const float4v*)hs;
    float4v a = in4[i * 2], b = in4[i * 2 + 1];
    bf16x8 v;
    v[0] = (short)f2bf(a.x); v[1] = (short)f2bf(a.y);
    v[2] = (short)f2bf(a.z); v[3] = (short)f2bf(a.w);
    v[4] = (short)f2bf(b.x); v[5] = (short)f2bf(b.y);
    v[6] = (short)f2bf(b.z); v[7] = (short)f2bf(b.w);
    *(bf16x8*)&hsB[(size_t)i * 8] = v;
    return;
  }
  if (bx < 3072) {                       // W[k][n] -> WB[mat*1024+n][k], LDS xpose
    int idx = bx - 2048;
    int mat = idx >> 8, sub = idx & 255;
    const float* W = (mat == 0) ? W0 : (mat == 1) ? W1 : (mat == 2) ? W2 : W3;
    int k0 = (sub >> 4) * 64, n0 = (sub & 15) * 64;
#pragma unroll
    for (int p = 0; p < 4; ++p) {
      int chunk = p * 256 + tid;
      int row = chunk >> 4, cp = chunk & 15;
      float4v v = *(const float4v*)&W[(size_t)(k0 + row) * 1024 + n0 + cp * 4];
      u16x4 o; o.x = f2bf(v.x); o.y = f2bf(v.y); o.z = f2bf(v.z); o.w = f2bf(v.w);
      *(u16x4*)&T[row][cp * 4] = o;
    }
    __syncthreads();
#pragma unroll
    for (int p = 0; p < 2; ++p) {
      int chunk = p * 256 + tid;
      int nrow = chunk >> 3, cp = chunk & 7;
      bf16x8 v;
#pragma unroll
      for (int e = 0; e < 8; ++e) v[e] = (short)T[cp * 8 + e][nrow];
      *(bf16x8*)&WB[(size_t)(mat * 1024 + n0 + nrow) * 1024 + k0 + cp * 8] = v;
    }
    return;
  }
  {                                      // gq partial sums (+ acc3 zero)
    int idx = bx - 3072;                 // 64 blocks
    if (idx == 0 && tid < 3) acc3[tid] = 0.f;
    int kb = idx >> 1, b = idx & 1;
    int col0 = tid * 4;
    float4v s = {0.f, 0.f, 0.f, 0.f};
    for (int k = kb * 32; k < kb * 32 + 32; ++k) {
      float g = ge[b * 1024 + k];
      float4v w = *(const float4v*)&Wgq[(size_t)k * 1024 + col0];
      s.x += g * w.x; s.y += g * w.y; s.z += g * w.z; s.w += g * w.w;
    }
    *(float4v*)&gq_part[(size_t)idx * 1024 + col0] = s;  // [kb*2+b][1024]
  }
}

// ---------------- projection GEMM + fused influence --------------------------
// grid 1024 = exactly 4 blocks/CU x 256 CU (no tail round).
// K -> Kt4[b][h][g=k/4][s:2048][4];  V -> Vt4[b][g=s/4][d:1024][4].
__global__ __launch_bounds__(256, 4) void gemm_qkvg(
    const u16* __restrict__ A, const u16* __restrict__ Bw,
    const float* __restrict__ bq, const float* __restrict__ bk,
    const float* __restrict__ bv, const float* __restrict__ bgk,
    const float* __restrict__ bgq, const float* __restrict__ gq_part,
    u16* __restrict__ Qb, u16* __restrict__ Kt4, u16* __restrict__ Vt4,
    float* __restrict__ acc3) {
  __shared__ __align__(16) u16 As[2][128 * 32];
  __shared__ __align__(16) u16 Bs[2][128 * 32];
  __shared__ float redI[4];
  const int tid = threadIdx.x, lane = tid & 63, wv = tid >> 6;
  const int li = lane & 15, quad = lane >> 4;
  const int bid = blockIdx.x;
  const int nb = bid & 31, mb = bid >> 5;
  const u16* Ap = A + (size_t)(mb * 128) * 1024;
  const u16* Bp = Bw + (size_t)(nb * 128) * 1024;
  const int wm0 = (wv >> 1) * 64, wn0 = (wv & 1) * 64;

  f32x4 acc[4][4];
#pragma unroll
  for (int t = 0; t < 4; ++t)
#pragma unroll
    for (int u = 0; u < 4; ++u) acc[t][u] = (f32x4){0.f, 0.f, 0.f, 0.f};

  // prologue: stage kt=0 into buf 0
#pragma unroll
  for (int jj = 0; jj < 2; ++jj) {
    int j = wv * 2 + jj;
    int row = j * 16 + (lane >> 2);
    int co = lane & 3;
    gl_lds16(Ap + (size_t)row * 1024 + co * 8, &As[0][j * 512]);
    gl_lds16(Bp + (size_t)row * 1024 + co * 8, &Bs[0][j * 512]);
  }

  for (int kt = 0; kt < 32; ++kt) {
    const int cur = kt & 1;
    __syncthreads();                     // drains loads for buf cur
    if (kt < 31) {                       // prefetch kt+1 into other buffer
#pragma unroll
      for (int jj = 0; jj < 2; ++jj) {
        int j = wv * 2 + jj;
        int row = j * 16 + (lane >> 2);
        int co = lane & 3;
        gl_lds16(Ap + (size_t)row * 1024 + (kt + 1) * 32 + co * 8, &As[cur ^ 1][j * 512]);
        gl_lds16(Bp + (size_t)row * 1024 + (kt + 1) * 32 + co * 8, &Bs[cur ^ 1][j * 512]);
      }
    }
    bf16x8 af[4], bf[4];
#pragma unroll
    for (int t = 0; t < 4; ++t)
      af[t] = *(const bf16x8*)&As[cur][(wm0 + t * 16 + li) * 32 + quad * 8];
#pragma unroll
    for (int u = 0; u < 4; ++u)
      bf[u] = *(const bf16x8*)&Bs[cur][(wn0 + u * 16 + li) * 32 + quad * 8];
#pragma unroll
    for (int t = 0; t < 4; ++t)
#pragma unroll
      for (int u = 0; u < 4; ++u)
        acc[t][u] = __builtin_amdgcn_mfma_f32_16x16x32_bf16(af[t], bf[u], acc[t][u], 0, 0, 0);
  }

  const int nbase = nb * 128;
  const int mat = nbase >> 10;           // block never straddles matrices
  if (mat == 3) {
    // ---- fused influence: wave owns 64 rows x 1 full head (64 cols) ----
    const int colbase = nbase & 1023;
    const int bat = (mb * 128) >> 11;    // batch index of this block's rows
    float gqv[4], bgkv[4];
#pragma unroll
    for (int u2 = 0; u2 < 4; ++u2) {
      int col = colbase + wn0 + u2 * 16 + li;
      float g = bgq[col];
      for (int kb = 0; kb < 32; ++kb)
        g += gq_part[(size_t)(kb * 2 + bat) * 1024 + col];
      gqv[u2] = g;
      bgkv[u2] = bgk[col];
    }
    float infl = 0.f;
#pragma unroll
    for (int t = 0; t < 4; ++t)
#pragma unroll
      for (int r = 0; r < 4; ++r) {
        float v = (acc[t][0][r] + bgkv[0]) * gqv[0];
        v = __builtin_fmaf(acc[t][1][r] + bgkv[1], gqv[1], v);
        v = __builtin_fmaf(acc[t][2][r] + bgkv[2], gqv[2], v);
        v = __builtin_fmaf(acc[t][3][r] + bgkv[3], gqv[3], v);
        v += __shfl_xor(v, 1, 64); v += __shfl_xor(v, 2, 64);
        v += __shfl_xor(v, 4, 64); v += __shfl_xor(v, 8, 64);
        infl += fabsf(v);              // all 16 li-lanes hold same v
      }
    infl = (li == 0) ? infl : 0.f;
    infl += __shfl_xor(infl, 16, 64);
    infl += __shfl_xor(infl, 32, 64);
    if (lane == 0) redI[wv] = infl;
    __syncthreads();
    if (tid == 0) atomicAdd(&acc3[2], redI[0] + redI[1] + redI[2] + redI[3]);
  } else if (mat == 2) {
    // V -> Vt4[b][g=s/4][d:1024][4s], one b64 per (t,u)
#pragma unroll
    for (int t = 0; t < 4; ++t)
#pragma unroll
      for (int u = 0; u < 4; ++u) {
        int col = (nbase & 1023) + wn0 + u * 16 + li;
        float bb = bv[col];
        int row = mb * 128 + wm0 + t * 16 + quad * 4;  // s%4 == 0
        int b = row >> 11, s = row & 2047, g = s >> 2;
        uint2 w;
        w.x = pk2(acc[t][u][1] + bb, acc[t][u][0] + bb);
        w.y = pk2(acc[t][u][3] + bb, acc[t][u][2] + bb);
        *(uint2*)&Vt4[(((size_t)b * 512 + g) * 1024 + col) * 4] = w;
      }
  } else if (mat == 1) {
    // K -> Kt4[b][h][g=k/4][s:2048][4k], scalar stores (8B-local per r)
#pragma unroll
    for (int t = 0; t < 4; ++t)
#pragma unroll
      for (int u = 0; u < 4; ++u) {
        int col = (nbase & 1023) + wn0 + u * 16 + li;
        int h = col >> 6, g = (col & 63) >> 2, r4 = col & 3;
        float bb = bk[col];
        u16* base = &Kt4[(((size_t)h * 16 + g) * 2048) * 4 + r4];
#pragma unroll
        for (int r = 0; r < 4; ++r) {
          int row = mb * 128 + wm0 + t * 16 + quad * 4 + r;
          int b = row >> 11, s = row & 2047;
          base[((size_t)b * 16 * 16 * 2048 + s) * 4] = f2bf(acc[t][u][r] + bb);
        }
      }
  } else {
    // Q (pre-scaled by 1/sqrt(64) * log2(e) for exp2-based softmax)
#pragma unroll
    for (int t = 0; t < 4; ++t)
#pragma unroll
      for (int u = 0; u < 4; ++u) {
        int col = (nbase & 1023) + wn0 + u * 16 + li;
        float bb = bq[col];
#pragma unroll
        for (int r = 0; r < 4; ++r) {
          int row = mb * 128 + wm0 + t * 16 + quad * 4 + r;
          Qb[(size_t)row * 1024 + col] = f2bf((acc[t][u][r] + bb) * 0.18033688f);
        }
      }
  }
}

// ---------------- flash attention: 32x32 MFMA, phase-batched -----------------
// grid 512 x 256. bh = bx&31 (XCD-L2 locality), qb = bx>>5.
__global__ __launch_bounds__(256, 2) void attn_kernel(
    const u16* __restrict__ Qb, const u16* __restrict__ Kt4,
    const u16* __restrict__ Vt4, float* __restrict__ out,
    float* __restrict__ acc3 /*[0]=ent,[1]=conc*/) {
  __shared__ __align__(16) u16 Ks[2][8192];   // [g:16][s_phys:128][4k]
  __shared__ __align__(16) u16 Vs[2][8192];   // [g:32][d_phys:64][4s]
  __shared__ float red[8];

  const int tid = threadIdx.x, lane = tid & 63, wv = tid >> 6;
  const int q_l = lane & 31, half = lane >> 5;
  const int x8 = half << 3;              // row-XOR for bank spread
  const int bx = blockIdx.x;
  const int bh = bx & 31, qb = bx >> 5;
  const int b = bh >> 4, h = bh & 15;

  const u16* Qp = Qb + (size_t)(b * 2048 + qb * 128 + wv * 32 + q_l) * 1024 + h * 64;
  const u16* Kp4 = Kt4 + ((size_t)(b * 16 + h) * 16) * 2048 * 4;
  const u16* Vp4 = Vt4 + ((size_t)b * 512 * 1024 + h * 64) * 4;

  // Q^T B-frags in registers: lane (q=q_l, half) holds k = s*16 + half*8 + j
  bf16x8 qf[4];
#pragma unroll
  for (int s = 0; s < 4; ++s)
    qf[s] = *(const bf16x8*)&Qp[s * 16 + half * 8];

  f32x2 mx2 = {-3.0e38f, -3.0e38f}, ps2 = {0.f, 0.f}, es2 = {0.f, 0.f};
  f32x16 accO[2];   // O^T: rows d = dt*32 + (reg&3)+8*(reg>>2)+4*half, col q
#pragma unroll
  for (int dt = 0; dt < 2; ++dt)
#pragma unroll
    for (int r = 0; r < 16; ++r) accO[dt][r] = 0.f;

  // staging lane->source indices (XOR-8 so wave-halves hit different banks)
  const int ksrc = (2 * lane);           // ^x8g per column below
  const int vlane_d = 2 * (lane & 31);

  // prologue: stage tile 0 into buf 0
#pragma unroll
  for (int jj = 0; jj < 4; ++jj) {
    int g = wv * 4 + jj;
    int xg = ((g >> 1) & 1) << 3;
    gl_lds16(Kp4 + ((size_t)g * 2048 + (ksrc ^ xg)) * 4, &Ks[0][g * 512]);
  }
#pragma unroll
  for (int jj = 0; jj < 4; ++jj) {
    int j = wv * 4 + jj;
    int g = 2 * j + (lane >> 5);
    int xg = (g & 1) << 3;
    gl_lds16(Vp4 + ((size_t)g * 1024 + (vlane_d ^ xg)) * 4, &Vs[0][j * 512]);
  }

  for (int kt = 0; kt < 16; ++kt) {
    const int cur = kt & 1;
    __syncthreads();                     // drains tile-kt loads
    if (kt < 15) {                       // prefetch kt+1; compute hides it
#pragma unroll
      for (int jj = 0; jj < 4; ++jj) {
        int g = wv * 4 + jj;
        int xg = ((g >> 1) & 1) << 3;
        gl_lds16(Kp4 + ((size_t)g * 2048 + (kt + 1) * 128 + (ksrc ^ xg)) * 4,
                 &Ks[cur ^ 1][g * 512]);
      }
#pragma unroll
      for (int jj = 0; jj < 4; ++jj) {
        int j = wv * 4 + jj;
        int g = 2 * j + (lane >> 5);
        int xg = (g & 1) << 3;
        gl_lds16(Vp4 + ((size_t)((kt + 1) * 32 + g) * 1024 + (vlane_d ^ xg)) * 4,
                 &Vs[cur ^ 1][j * 512]);
      }
    }
    const u16* KsC = &Ks[cur][0];
    const u16* VsC = &Vs[cur][0];

    // ---- phase 1: all four 32-key S^T tiles (independent MFMA chains) ----
    f32x16 c[4];
#pragma unroll
    for (int u = 0; u < 4; ++u) {
      const int keyp = (u * 32 + q_l) ^ x8;    // physical row (XOR-8 stored)
      f32x16 cc;
#pragma unroll
      for (int r = 0; r < 16; ++r) cc[r] = 0.f;
#pragma unroll
      for (int s = 0; s < 4; ++s) {
        int g0 = s * 4 + half * 2;
        uint2 k0 = *(const uint2*)&KsC[g0 * 512 + keyp * 4];
        uint2 k1 = *(const uint2*)&KsC[(g0 + 1) * 512 + keyp * 4];
        cc = __builtin_amdgcn_mfma_f32_32x32x16_bf16(
            mk8(k0.x, k0.y, k1.x, k1.y), qf[s], cc, 0, 0, 0);
      }
      c[u] = cc;
    }
    // ---- phase 2: softmax stats + exp over all 64 scores ----
#pragma unroll
    for (int u = 0; u < 4; ++u)
#pragma unroll
      for (int r = 0; r < 8; ++r) {
        f32x2 sv = {c[u][2 * r], c[u][2 * r + 1]};
        mx2 = __builtin_elementwise_max(mx2, sv);
        f32x2 pe = {EXP2(sv.x), EXP2(sv.y)};
        ps2 += pe;
        es2 += pe * sv;                  // v_pk_fma_f32
        c[u][2 * r] = pe.x; c[u][2 * r + 1] = pe.y;
      }
    // ---- phase 3: pack + PV (C regs ARE the B-operand pattern) ----
#pragma unroll
    for (int u = 0; u < 4; ++u) {
      bf16x8 bf0 = mk8(pk2(c[u][1], c[u][0]),   pk2(c[u][3], c[u][2]),
                       pk2(c[u][5], c[u][4]),   pk2(c[u][7], c[u][6]));
      bf16x8 bf1 = mk8(pk2(c[u][9], c[u][8]),   pk2(c[u][11], c[u][10]),
                       pk2(c[u][13], c[u][12]), pk2(c[u][15], c[u][14]));
#pragma unroll
      for (int dt = 0; dt < 2; ++dt) {
        int dp = (dt * 32 + q_l) ^ x8;   // physical d row
        uint2 v0 = *(const uint2*)&VsC[(u * 8 + half) * 256 + dp * 4];
        uint2 v1 = *(const uint2*)&VsC[(u * 8 + 2 + half) * 256 + dp * 4];
        accO[dt] = __builtin_amdgcn_mfma_f32_32x32x16_bf16(
            mk8(v0.x, v0.y, v1.x, v1.y), bf0, accO[dt], 0, 0, 0);
        uint2 v2 = *(const uint2*)&VsC[(u * 8 + 4 + half) * 256 + dp * 4];
        uint2 v3 = *(const uint2*)&VsC[(u * 8 + 6 + half) * 256 + dp * 4];
        accO[dt] = __builtin_amdgcn_mfma_f32_32x32x16_bf16(
            mk8(v2.x, v2.y, v3.x, v3.y), bf1, accO[dt], 0, 0, 0);
      }
    }
  }

  // epilogue: each lane owns query q_l (duplicated across half)
  float l_st = ps2.x + ps2.y, e_st = es2.x + es2.y, m_st = fmaxf(mx2.x, mx2.y);
  float lsum = l_st + __shfl_xor(l_st, 32, 64);
  float esum = e_st + __shfl_xor(e_st, 32, 64);
  float mm = fmaxf(m_st, __shfl_xor(m_st, 32, 64));
  float inv = 1.0f / lsum;
  float entw = __logf(lsum) - 0.69314718f * esum * inv;  // s' in log2 units
  float concw = EXP2(mm) * inv;

  float* outp = out + (size_t)(b * 2048 + qb * 128 + wv * 32 + q_l) * 1024 + h * 64;
#pragma unroll
  for (int dt = 0; dt < 2; ++dt)
#pragma unroll
    for (int g = 0; g < 4; ++g) {
      float4v o;
      o.x = accO[dt][4 * g + 0] * inv; o.y = accO[dt][4 * g + 1] * inv;
      o.z = accO[dt][4 * g + 2] * inv; o.w = accO[dt][4 * g + 3] * inv;
      *(float4v*)&outp[dt * 32 + 8 * g + 4 * half] = o;
    }

#pragma unroll
  for (int off = 1; off < 64; off <<= 1) {
    entw += __shfl_xor(entw, off, 64);
    concw += __shfl_xor(concw, off, 64);
  }
  if (lane == 0) { red[wv] = entw * 0.5f; red[4 + wv] = concw * 0.5f; }  // /2 dup
  __syncthreads();
  if (tid == 0) {
    atomicAdd(&acc3[0], red[0] + red[1] + red[2] + red[3]);
    atomicAdd(&acc3[1], red[4] + red[5] + red[6] + red[7]);
  }
}

__global__ void finalize(const float* __restrict__ acc3, float* __restrict__ out) {
  if (threadIdx.x == 0) {
    out[0] = acc3[0] * (1.f / 65536.f);  // entropy
    out[1] = acc3[2] * (1.f / 65536.f);  // influence
    out[2] = acc3[1] * (1.f / 65536.f);  // concentration
  }
}

extern "C" void kernel_launch(void* const* d_in, const int* in_sizes, int n_in,
                              void* d_out, int out_size, void* d_ws, size_t ws_size,
                              hipStream_t stream) {
  (void)in_sizes; (void)n_in; (void)out_size; (void)ws_size;
  const float* hs  = (const float*)d_in[0];
  const float* ge  = (const float*)d_in[1];
  const float* Wq  = (const float*)d_in[2];
  const float* bq  = (const float*)d_in[3];
  const float* Wk  = (const float*)d_in[4];
  const float* bk  = (const float*)d_in[5];
  const float* Wv  = (const float*)d_in[6];
  const float* bv  = (const float*)d_in[7];
  const float* Wgq = (const float*)d_in[8];
  const float* bgq = (const float*)d_in[9];
  const float* Wgk = (const float*)d_in[10];
  const float* bgk = (const float*)d_in[11];

  char* ws = (char*)d_ws;
  u16* hsB  = (u16*)(ws);
  u16* WB   = (u16*)(ws + (size_t)(8 << 20));
  u16* Qb   = (u16*)(ws + (size_t)(16 << 20));
  u16* Kt4  = (u16*)(ws + (size_t)(24 << 20));
  u16* Vt4  = (u16*)(ws + (size_t)(32 << 20));
  float* gq_part = (float*)(ws + (size_t)(48 << 20));            // 256 KB
  float* acc3    = (float*)(ws + (size_t)(48 << 20) + 524288);
  float* out = (float*)d_out;

  prep<<<3136, 256, 0, stream>>>(hs, Wq, Wk, Wv, Wgk, ge, Wgq, hsB, WB, gq_part, acc3);
  gemm_qkvg<<<1024, 256, 0, stream>>>(hsB, WB, bq, bk, bv, bgk, bgq, gq_part,
                                      Qb, Kt4, Vt4, acc3);
  attn_kernel<<<512, 256, 0, stream>>>(Qb, Kt4, Vt4, out, acc3);
  finalize<<<1, 64, 0, stream>>>(acc3, out + 4194304);
}